// Round 20
// baseline (73.454 us; speedup 1.0000x reference)
//
#include <hip/hip_runtime.h>
#include <math.h>

#define NN 100000
#define CC 128
#define KK 32
#define BG 16
#define EPSF 1e-9f

#define NTILES 1563   // ceil(NN/64)

// d_out float layout: out[16][32][128] | s[100000][32] | mu[16][32][2] | losses[9]
#define S_OFF 65536
#define MU_OFF 3265536
#define LOSS_OFF 3266560

// ws float layout:
//   [0 .. 2048)      per-block entropy partials (plain stores)
//   [2048 .. 4096)   stats [4 stats][16 b][32 k]
//   [4096 .. 4112)   first-full-tile[b] (int)
//   [4112 .. 4128)   last-full-tile[b]  (int)
//   byte 16896: W1 frags (32 KB); byte 49664: W2 frags (8 KB)
//   byte 65536: pool partials [NTILES][32][128] fp16 (12.8 MB)
//   byte 65536+12804096: precomputed gumbel g [NN][32] fp32 (12.8 MB)
#define WS_ENTARR 0
#define WS_STAT 2048
#define WS_FIRST 4096
#define WS_LAST 4112

#define W1B_OFF_BYTES 16896
#define W2B_OFF_BYTES 49664
#define WS_PART_BYTE 65536
#define WS_G_BYTE (65536ull + (unsigned long long)NTILES * 4096ull * 2ull)
#define WS_NEEDED_BYTES (WS_G_BYTE + (unsigned long long)NN * KK * 4ull)

typedef __attribute__((ext_vector_type(8))) _Float16 half8;
typedef __attribute__((ext_vector_type(4))) _Float16 half4v;
typedef __attribute__((ext_vector_type(4))) float float4v;

#define MFMAH(a, b, c) __builtin_amdgcn_mfma_f32_16x16x32_f16((a), (b), (c), 0, 0, 0)

// ---------------- prep: W frags + ranges + zero-init + gumbel precompute ----------------
// grid: 256 blocks x 256
__global__ __launch_bounds__(256) void k_prep(const float* __restrict__ W1,
                                              const float* __restrict__ W2,
                                              const int* __restrict__ batch,
                                              const float* __restrict__ gum,
                                              _Float16* __restrict__ wW1,
                                              _Float16* __restrict__ wW2,
                                              int* __restrict__ firstp,
                                              int* __restrict__ lastp,
                                              float* __restrict__ dout,
                                              float* __restrict__ ws,
                                              float* __restrict__ gpre) {
    int tid = blockIdx.x * 256 + threadIdx.x;   // 0..65535

    // gumbel precompute: g = -log(-log(u+eps)+eps), float4 strided
    if (gpre != nullptr) {
        const float4* g4 = (const float4*)gum;
        float4* o4 = (float4*)gpre;
        for (int i = tid; i < NN * KK / 4; i += 65536) {
            float4 u = g4[i];
            float4 o;
            o.x = -__logf(-__logf(u.x + EPSF) + EPSF);
            o.y = -__logf(-__logf(u.y + EPSF) + EPSF);
            o.z = -__logf(-__logf(u.z + EPSF) + EPSF);
            o.w = -__logf(-__logf(u.w + EPSF) + EPSF);
            o4[i] = o;
        }
    }

    if (tid < 4096) {
        // zero dout pooled-out region (256 KB) : 4 float4 per thread
        float4 z4 = make_float4(0.f, 0.f, 0.f, 0.f);
#pragma unroll
        for (int i = 0; i < 4; ++i) ((float4*)dout)[tid + i * 4096] = z4;
        // zero ws entropy+stats (16 KB)
        ws[tid] = 0.f;
    }

    if (tid < 8 * 4 * 64) {                       // W1: nt(8), ks(4), lane(64)
        int l = tid & 63, ks = (tid >> 6) & 3, nt = tid >> 8;
        int n = nt * 16 + (l & 15);
        int cb = ks * 32 + (l >> 4) * 8;
        half8 H;
#pragma unroll
        for (int j = 0; j < 8; ++j) H[j] = (_Float16)W1[(size_t)(cb + j) * CC + n];
        ((half8*)wW1)[(nt * 4 + ks) * 64 + l] = H;
    } else if (tid < 2048 + 512) {                // W2: nt(2), ks(4), lane(64)
        int t2 = tid - 2048;
        int l = t2 & 63, ks = (t2 >> 6) & 3, nt = t2 >> 8;
        int n = nt * 16 + (l & 15);
        int cb = ks * 32 + (l >> 4) * 8;
        half8 H;
#pragma unroll
        for (int j = 0; j < 8; ++j) H[j] = (_Float16)W2[(size_t)(cb + j) * KK + n];
        ((half8*)wW2)[(nt * 4 + ks) * 64 + l] = H;
    } else if (tid >= 2560 && tid < 2560 + 16) {
        // full-tile range of graph b (graph 15's hi padded to NTILES*64)
        int b = tid - 2560;
        int lo = 0, hi = NN;
        while (lo < hi) { int mid = (lo + hi) >> 1; if (batch[mid] < b) lo = mid + 1; else hi = mid; }
        int lob = lo;
        lo = 0; hi = NN;
        while (lo < hi) { int mid = (lo + hi) >> 1; if (batch[mid] < b + 1) lo = mid + 1; else hi = mid; }
        int hib = (b == BG - 1) ? NTILES * 64 : lo;
        firstp[b] = (lob + 63) >> 6;
        lastp[b]  = (hib >> 6) - 1;
    }
}

// ---------------- fused single-tile: MLP (fp16 MFMA) + gumbel softmax + stats + pooling ----------------
__global__ __launch_bounds__(256, 4) void k_assign(
    const float* __restrict__ x, const int* __restrict__ batch,
    const float* __restrict__ pos, const float* __restrict__ gum,
    const float* __restrict__ b1, const float* __restrict__ b2,
    const float* __restrict__ scaling, const float* __restrict__ amask,
    const _Float16* __restrict__ wW1, const _Float16* __restrict__ wW2,
    float* __restrict__ dout, float* __restrict__ ws,
    _Float16* __restrict__ part, const float* __restrict__ gpre)
{
    __shared__ _Float16 xh[64][136];   // x fp16, live all kernel (pool B-source)
    __shared__ _Float16 hb[64][136];   // h fp16; dead after GEMM2 -> aliased as sbuf/pt
    __shared__ _Float16 st[32][72];    // s^T fp16 (pooling A + stats)
    __shared__ float lpx[64], lpy[64], lpsq[64];
    __shared__ int lbat[64];
    float* sbuf = (float*)&hb[0][0];             // [4 stats][8 ch][32 k] + [4] entropy partials
    _Float16* pt = (_Float16*)(sbuf + 1088);     // pool tile stage [32][128] fp16 (8 KB)

    const int t = threadIdx.x;
    const bool usep = (part != nullptr);
    // bijective XCD-chunked swizzle
    const int orig = blockIdx.x;
    const int qq = NTILES >> 3, rr8 = NTILES & 7;   // 195, 3
    const int xcd = orig & 7, sidx = orig >> 3;
    const int tile = (xcd < rr8 ? xcd * (qq + 1) : rr8 * (qq + 1) + (xcd - rr8) * qq) + sidx;
    const int n0 = tile * 64;

    const int l = t & 63;
    const int wv = __builtin_amdgcn_readfirstlane(t >> 6);
    const int li = l & 15;
    const int g16 = l >> 4;
    const int cc4 = (t & 31) * 4;
    const int nb = t >> 5;
    const int ca  = (2 * wv) * 16 + li;     // pooling c-col 0
    const int cb2 = (2 * wv + 1) * 16 + li; // pooling c-col 1
    const int sk = t & 31, sch = t >> 5;    // stats mapping

    const float scal = scaling[0];
    const float b2v0 = b2[li], b2v1 = b2[16 + li];
    const float am0 = amask[li], am1 = amask[16 + li];
    const float bv0 = b1[(2 * wv) * 16 + li];
    const float bv1 = b1[(2 * wv + 1) * 16 + li];

    // ---- stage x -> fp16 LDS (coalesced float4) ----
#pragma unroll
    for (int r = 0; r < 8; ++r) {
        int n = r * 8 + nb;
        int gn = n0 + n;
        float4 v = make_float4(0.f, 0.f, 0.f, 0.f);
        if (gn < NN) v = *(const float4*)(x + (size_t)gn * CC + cc4);
        *(half4v*)&xh[n][cc4] =
            (half4v){(_Float16)v.x, (_Float16)v.y, (_Float16)v.z, (_Float16)v.w};
    }
    if (t < 64) {
        int gn = n0 + t;
        float px = 0.f, py = 0.f; int bb = BG - 1;
        if (gn < NN) { px = pos[gn * 2]; py = pos[gn * 2 + 1]; bb = batch[gn]; }
        lpx[t] = px; lpy[t] = py; lpsq[t] = px * px + py * py; lbat[t] = bb;
    }

    // ---- gumbel (precomputed g if available) loads ----
    float gu[8];
#pragma unroll
    for (int r2 = 0; r2 < 4; ++r2) {
        int gn = n0 + wv * 16 + g16 * 4 + r2;
        bool valid = gn < NN;
        if (gpre != nullptr) {
            gu[r2 * 2]     = valid ? gpre[(size_t)gn * KK + li]      : 0.f;
            gu[r2 * 2 + 1] = valid ? gpre[(size_t)gn * KK + 16 + li] : 0.f;
        } else {
            float u0 = valid ? gum[(size_t)gn * KK + li]      : 0.5f;
            float u1 = valid ? gum[(size_t)gn * KK + 16 + li] : 0.5f;
            gu[r2 * 2]     = -__logf(-__logf(u0 + EPSF) + EPSF);
            gu[r2 * 2 + 1] = -__logf(-__logf(u1 + EPSF) + EPSF);
        }
    }
    __syncthreads();   // S1: x tile + meta staged

    // ---- GEMM1: h = x @ W1 ----
    float4v acc[4][2];
#pragma unroll
    for (int mt = 0; mt < 4; ++mt) {
        acc[mt][0] = (float4v){0.f, 0.f, 0.f, 0.f};
        acc[mt][1] = (float4v){0.f, 0.f, 0.f, 0.f};
    }
    const half8* W1B = (const half8*)wW1;
#pragma unroll
    for (int ks = 0; ks < 4; ++ks) {
        half8 bh0 = W1B[((2 * wv    ) * 4 + ks) * 64 + l];
        half8 bh1 = W1B[((2 * wv + 1) * 4 + ks) * 64 + l];
#pragma unroll
        for (int mt = 0; mt < 4; ++mt) {
            half8 ah = *(const half8*)&xh[mt * 16 + li][ks * 32 + g16 * 8];
            acc[mt][0] = MFMAH(ah, bh0, acc[mt][0]);
            acc[mt][1] = MFMAH(ah, bh1, acc[mt][1]);
        }
    }

    // ---- h = relu(acc + b1) -> hb ----
#pragma unroll
    for (int mt = 0; mt < 4; ++mt) {
#pragma unroll
        for (int r2 = 0; r2 < 4; ++r2) {
            int row = mt * 16 + g16 * 4 + r2;
            hb[row][(2 * wv) * 16 + li]     = (_Float16)fmaxf(acc[mt][0][r2] + bv0, 0.f);
            hb[row][(2 * wv + 1) * 16 + li] = (_Float16)fmaxf(acc[mt][1][r2] + bv1, 0.f);
        }
    }
    __syncthreads();   // S2: h visible to all waves

    // ---- GEMM2: logits = h @ W2 ----
    float4v acc2[2];
    acc2[0] = (float4v){0.f, 0.f, 0.f, 0.f};
    acc2[1] = (float4v){0.f, 0.f, 0.f, 0.f};
    const half8* W2B = (const half8*)wW2;
#pragma unroll
    for (int ks = 0; ks < 4; ++ks) {
        half8 ah = *(const half8*)&hb[wv * 16 + li][ks * 32 + g16 * 8];
        acc2[0] = MFMAH(ah, W2B[(0 * 4 + ks) * 64 + l], acc2[0]);
        acc2[1] = MFMAH(ah, W2B[(1 * 4 + ks) * 64 + l], acc2[1]);
    }

    // ---- softmax (no max-subtraction; g precomputed); s kept in regs, stored at END ----
    float ep_acc = 0.f;
    float sr0[4], sr1[4];
#pragma unroll
    for (int r2 = 0; r2 < 4; ++r2) {
        int m = wv * 16 + g16 * 4 + r2;
        int gn = n0 + m;
        bool valid = gn < NN;
        float lg0 = (acc2[0][r2] + b2v0) * scal; if (am0 == 0.f) lg0 = -1e9f;
        float lg1 = (acc2[1][r2] + b2v1) * scal; if (am1 == 0.f) lg1 = -1e9f;
        float z0 = lg0 + gu[r2 * 2];
        float z1 = lg1 + gu[r2 * 2 + 1];
        float e0 = __expf(z0), e1 = __expf(z1);
        float sm = e0 + e1;
        sm += __shfl_xor(sm, 1);
        sm += __shfl_xor(sm, 2);
        sm += __shfl_xor(sm, 4);
        sm += __shfl_xor(sm, 8);
        float inv = 1.f / sm;
        float s0 = e0 * inv, s1 = e1 * inv;
        if (!valid) { s0 = 0.f; s1 = 0.f; }
        sr0[r2] = s0; sr1[r2] = s1;
        st[li][m] = (_Float16)s0;
        st[16 + li][m] = (_Float16)s1;
        ep_acc += s0 * __logf(s0 + EPSF) + s1 * __logf(s1 + EPSF);
    }
    __syncthreads();   // S3: st ready; hb dead (sbuf/pt alias it)

    // ---- entropy: wave-reduce -> LDS partials ----
    ep_acc += __shfl_xor(ep_acc, 1);
    ep_acc += __shfl_xor(ep_acc, 2);
    ep_acc += __shfl_xor(ep_acc, 4);
    ep_acc += __shfl_xor(ep_acc, 8);
    ep_acc += __shfl_xor(ep_acc, 16);
    ep_acc += __shfl_xor(ep_acc, 32);
    if (l == 0) sbuf[1024 + wv] = ep_acc;

    // ---- segment geometry ----
    const int b0 = lbat[0], b63 = lbat[63];
    int cut = 64;
    if (b0 != b63) {
        for (int i = 1; i < 64; ++i) { if (lbat[i] != b0) { cut = i; break; } }
    }
    const int nseg = (b0 == b63) ? 1 : 2;

    // ---- stats: per-thread partials -> LDS -> 128 atomics per segment ----
#pragma unroll 1
    for (int sg = 0; sg < nseg; ++sg) {
        const int lo = sg ? cut : 0;
        const int hi = sg ? 64 : cut;
        const int bb = sg ? b63 : b0;
        float prs = 0.f, ppx = 0.f, ppy = 0.f, psq = 0.f;
#pragma unroll
        for (int r = 0; r < 8; ++r) {
            int n = sch * 8 + r;
            if (n >= lo && n < hi) {
                float sv = (float)st[sk][n];
                prs += sv; ppx += sv * lpx[n]; ppy += sv * lpy[n]; psq += sv * lpsq[n];
            }
        }
        if (sg) __syncthreads();
        sbuf[(0 * 8 + sch) * 32 + sk] = prs;
        sbuf[(1 * 8 + sch) * 32 + sk] = ppx;
        sbuf[(2 * 8 + sch) * 32 + sk] = ppy;
        sbuf[(3 * 8 + sch) * 32 + sk] = psq;
        __syncthreads();
        if (t < 128) {
            int stat = t >> 5, k = t & 31;
            float a = 0.f;
#pragma unroll
            for (int c = 0; c < 8; ++c) a += sbuf[(stat * 8 + c) * 32 + k];
            atomicAdd(ws + WS_STAT + stat * 512 + bb * KK + k, a);
        }
    }

    // ---- entropy partial: one plain store per block ----
    if (t == 0) {
        ws[WS_ENTARR + orig] = sbuf[1024] + sbuf[1025] + sbuf[1026] + sbuf[1027];
    }

    // ---- pooling: s^T x via MFMA (x frags read from still-live xh) ----
    float4v p00 = {0.f, 0.f, 0.f, 0.f}, p01 = p00, p10 = p00, p11 = p00;
    auto pool_flush = [&](int bb) {
        float* ob = dout + (size_t)bb * KK * CC;
#pragma unroll
        for (int r2 = 0; r2 < 4; ++r2) {
            int k0r = g16 * 4 + r2;
            atomicAdd(ob + k0r * CC + ca, p00[r2]);
            atomicAdd(ob + k0r * CC + cb2, p01[r2]);
            atomicAdd(ob + (16 + k0r) * CC + ca, p10[r2]);
            atomicAdd(ob + (16 + k0r) * CC + cb2, p11[r2]);
        }
        p00 = (float4v){0.f, 0.f, 0.f, 0.f}; p01 = p00; p10 = p00; p11 = p00;
    };
    if (b0 == b63) {
#pragma unroll
        for (int ksl = 0; ksl < 2; ++ksl) {
            half8 a0 = *(const half8*)&st[li][ksl * 32 + g16 * 8];
            half8 a1 = *(const half8*)&st[16 + li][ksl * 32 + g16 * 8];
            half8 v0, v1;
#pragma unroll
            for (int j = 0; j < 8; ++j) {
                int i = ksl * 32 + g16 * 8 + j;
                v0[j] = xh[i][ca];
                v1[j] = xh[i][cb2];
            }
            p00 = MFMAH(a0, v0, p00);
            p01 = MFMAH(a0, v1, p01);
            p10 = MFMAH(a1, v0, p10);
            p11 = MFMAH(a1, v1, p11);
        }
        if (usep) {
            // stage tile in LDS (fp16), then fully-coalesced 16B/lane writes
#pragma unroll
            for (int r2 = 0; r2 < 4; ++r2) {
                int k0r = g16 * 4 + r2;
                pt[k0r * CC + ca]         = (_Float16)p00[r2];
                pt[k0r * CC + cb2]        = (_Float16)p01[r2];
                pt[(16 + k0r) * CC + ca]  = (_Float16)p10[r2];
                pt[(16 + k0r) * CC + cb2] = (_Float16)p11[r2];
            }
            __syncthreads();   // S4 (block-uniform path)
            _Float16* pb = part + (size_t)tile * 4096 + t * 16;
            const _Float16* src = pt + t * 16;
            *(half8*)(pb)     = *(const half8*)(src);
            *(half8*)(pb + 8) = *(const half8*)(src + 8);
        } else {
            pool_flush(b0);
        }
    } else {
#pragma unroll 1
        for (int pass = 0; pass < 2; ++pass) {
            int lo = pass ? cut : 0;
            int hi = pass ? 64 : cut;
            int bb = pass ? b63 : b0;
#pragma unroll
            for (int ksl = 0; ksl < 2; ++ksl) {
                half8 a0, a1, v0, v1;
#pragma unroll
                for (int j = 0; j < 8; ++j) {
                    int i = ksl * 32 + g16 * 8 + j;
                    bool in = (i >= lo) && (i < hi);
                    a0[j] = in ? st[li][i] : (_Float16)0.f;
                    a1[j] = in ? st[16 + li][i] : (_Float16)0.f;
                    v0[j] = xh[i][ca];
                    v1[j] = xh[i][cb2];
                }
                p00 = MFMAH(a0, v0, p00);
                p01 = MFMAH(a0, v1, p01);
                p10 = MFMAH(a1, v0, p10);
                p11 = MFMAH(a1, v1, p11);
            }
            pool_flush(bb);
        }
    }

    // ---- deferred s stores (overlap; drain at endpgm) ----
#pragma unroll
    for (int r2 = 0; r2 < 4; ++r2) {
        int gn = n0 + wv * 16 + g16 * 4 + r2;
        if (gn < NN) {
            dout[S_OFF + (size_t)gn * KK + li]      = sr0[r2];
            dout[S_OFF + (size_t)gn * KK + 16 + li] = sr1[r2];
        }
    }
}

// ---------------- reduce pool partials into out + merged finalize ----------------
// grid: BG*16*8 + 1 blocks; last block computes losses/centroids
__global__ __launch_bounds__(256) void k_reduce(const _Float16* __restrict__ part,
                                                const int* __restrict__ firstp,
                                                const int* __restrict__ lastp,
                                                const float* __restrict__ ws,
                                                const float* __restrict__ amask,
                                                float* __restrict__ dout) {
    if (blockIdx.x < BG * 16 * 8) {
        if (part == nullptr) return;
        const int b   = blockIdx.x >> 7;
        const int elc = (blockIdx.x >> 3) & 15;
        const int sp  = blockIdx.x & 7;
        const int el  = elc * 256 + threadIdx.x;   // k*128+c
        const int lo = firstp[b], hi = lastp[b];
        if (lo > hi) return;
        const int count = hi - lo + 1;
        const int per = (count + 7) >> 3;
        const int t0 = lo + sp * per;
        if (t0 > hi) return;
        int t1 = t0 + per - 1; if (t1 > hi) t1 = hi;
        float s0 = 0.f, s1 = 0.f;
        int tt = t0;
        for (; tt + 1 <= t1; tt += 2) {
            s0 += (float)part[(size_t)tt * 4096 + el];
            s1 += (float)part[(size_t)(tt + 1) * 4096 + el];
        }
        if (tt <= t1) s0 += (float)part[(size_t)tt * 4096 + el];
        atomicAdd(dout + (size_t)b * 4096 + el, s0 + s1);
        return;
    }

    // ---- finalize losses + centroids (single block) ----
    __shared__ float avg[32], csum[32], cpx[32], cpy[32], csq[32];
    __shared__ float lmu[16][32][2];
    __shared__ float red[4], ered[4];
    const int t = threadIdx.x;

    float esum = 0.f;
    for (int i = t; i < NTILES; i += 256) esum += ws[WS_ENTARR + i];
    esum += __shfl_xor(esum, 1);
    esum += __shfl_xor(esum, 2);
    esum += __shfl_xor(esum, 4);
    esum += __shfl_xor(esum, 8);
    esum += __shfl_xor(esum, 16);
    esum += __shfl_xor(esum, 32);
    if ((t & 63) == 0) ered[t >> 6] = esum;

    if (t < 32) {
        float a = 0.f, px = 0.f, py = 0.f, sq = 0.f;
        for (int b = 0; b < BG; ++b) {
            a  += ws[WS_STAT + 0 * 512 + b * KK + t];
            px += ws[WS_STAT + 1 * 512 + b * KK + t];
            py += ws[WS_STAT + 2 * 512 + b * KK + t];
            sq += ws[WS_STAT + 3 * 512 + b * KK + t];
        }
        csum[t] = a; cpx[t] = px; cpy[t] = py; csq[t] = sq;
        avg[t] = a / (float)NN;
    }
    for (int idx = t; idx < BG * KK; idx += 256) {
        float den = ws[WS_STAT + idx] + EPSF;
        float mx = ws[WS_STAT + 512 + idx] / den;
        float my = ws[WS_STAT + 1024 + idx] / den;
        int b = idx >> 5, k = idx & 31;
        lmu[b][k][0] = mx; lmu[b][k][1] = my;
        dout[MU_OFF + idx * 2] = mx;
        dout[MU_OFF + idx * 2 + 1] = my;
    }
    __syncthreads();
    float sep = 0.f;
    for (int idx = t; idx < BG * KK * KK; idx += 256) {
        int b = idx >> 10, k1 = (idx >> 5) & 31, k2 = idx & 31;
        if (k1 != k2) {
            float dx = lmu[b][k1][0] - lmu[b][k2][0];
            float dy = lmu[b][k1][1] - lmu[b][k2][1];
            sep += 1.f / (dx * dx + dy * dy + 1.f);
        }
    }
    for (int off = 32; off; off >>= 1) sep += __shfl_down(sep, off);
    if ((t & 63) == 0) red[t >> 6] = sep;
    __syncthreads();
    if (t == 0) {
        float sept = red[0] + red[1] + red[2] + red[3];
        float separation = sept / ((float)(KK * (KK - 1)) + EPSF);
        float entropy = -(ered[0] + ered[1] + ered[2] + ered[3]) / (float)NN;
        float diversity = 0.f, pruning = 0.f, msum = 0.f, entavg = 0.f, bal = 0.f, mxa = 0.f, spatial = 0.f;
        const float up = 1.f / (float)KK;
        for (int k = 0; k < KK; ++k) {
            float a = avg[k];
            diversity += up * logf(up / (a + EPSF));
            float mk = amask[k];
            pruning += fabsf(a * (1.f - mk));
            msum += mk;
            entavg -= a * logf(a + EPSF);
            bal += a * logf(a * (float)KK + EPSF);
            mxa = fmaxf(mxa, a);
            float den = csum[k] + EPSF;
            float mux = cpx[k] / den, muy = cpy[k] / den;
            spatial += csq[k] / den - (mux * mux + muy * muy);
        }
        pruning *= up;
        spatial *= up;
        const float lk = logf((float)KK);
        float collapse = ((lk - entavg) / lk + fmaxf(mxa - 2.f / (float)KK, 0.f)) * 2.0f;
        float sparsity = (msum / (float)KK) * 0.01f;
        dout[LOSS_OFF + 0] = entropy;
        dout[LOSS_OFF + 1] = diversity;
        dout[LOSS_OFF + 2] = spatial;
        dout[LOSS_OFF + 3] = pruning;
        dout[LOSS_OFF + 4] = sparsity;
        dout[LOSS_OFF + 5] = 0.f;
        dout[LOSS_OFF + 6] = collapse;
        dout[LOSS_OFF + 7] = bal;
        dout[LOSS_OFF + 8] = separation;
    }
}

extern "C" void kernel_launch(void* const* d_in, const int* in_sizes, int n_in,
                              void* d_out, int out_size, void* d_ws, size_t ws_size,
                              hipStream_t stream) {
    const float* x     = (const float*)d_in[0];
    const int*   batch = (const int*)d_in[1];
    const float* pos   = (const float*)d_in[2];
    const float* gum   = (const float*)d_in[3];
    const float* W1    = (const float*)d_in[4];
    const float* b1    = (const float*)d_in[5];
    const float* W2    = (const float*)d_in[6];
    const float* b2    = (const float*)d_in[7];
    const float* scal  = (const float*)d_in[8];
    const float* amask = (const float*)d_in[9];
    float* dout = (float*)d_out;
    float* ws   = (float*)d_ws;
    _Float16* wW1 = (_Float16*)((char*)d_ws + W1B_OFF_BYTES);
    _Float16* wW2 = (_Float16*)((char*)d_ws + W2B_OFF_BYTES);
    int* firstp = (int*)(ws + WS_FIRST);
    int* lastp  = (int*)(ws + WS_LAST);
    const bool usep = (ws_size >= (size_t)WS_NEEDED_BYTES);
    _Float16* partp = usep ? (_Float16*)((char*)d_ws + WS_PART_BYTE) : nullptr;
    float* gprep    = usep ? (float*)((char*)d_ws + WS_G_BYTE) : nullptr;

    k_prep<<<256, 256, 0, stream>>>(W1, W2, batch, gum, wW1, wW2, firstp, lastp,
                                    dout, ws, gprep);
    k_assign<<<NTILES, 256, 0, stream>>>(x, batch, pos, gum, b1, b2,
                                         scal, amask, wW1, wW2, dout, ws, partp, gprep);
    k_reduce<<<BG * 16 * 8 + 1, 256, 0, stream>>>(partp, firstp, lastp, ws, amask, dout);
}

// Round 21
// 70.865 us; speedup vs baseline: 1.0365x; 1.0365x over previous
//
#include <hip/hip_runtime.h>
#include <math.h>

#define NN 100000
#define CC 128
#define KK 32
#define BG 16
#define EPSF 1e-9f

#define NTILES 1563   // ceil(NN/64)

// d_out float layout: out[16][32][128] | s[100000][32] | mu[16][32][2] | losses[9]
#define S_OFF 65536
#define MU_OFF 3265536
#define LOSS_OFF 3266560

// ws float layout:
//   [0 .. 2048)      per-block entropy partials (plain stores)
//   [2048 .. 4096)   stats [4 stats][16 b][32 k]
//   [4096 .. 4112)   first-full-tile[b] (int)
//   [4112 .. 4128)   last-full-tile[b]  (int)
//   byte 16896: W1 frags (32 KB); byte 49664: W2 frags (8 KB)
//   byte 65536: pool partials [NTILES][32][128] fp16 (12.8 MB, if ws fits)
#define WS_ENTARR 0
#define WS_STAT 2048
#define WS_FIRST 4096
#define WS_LAST 4112

#define W1B_OFF_BYTES 16896
#define W2B_OFF_BYTES 49664
#define WS_PART_BYTE 65536
#define WS_NEEDED_BYTES (65536ull + (unsigned long long)NTILES * 4096ull * 2ull)

typedef __attribute__((ext_vector_type(8))) _Float16 half8;
typedef __attribute__((ext_vector_type(4))) _Float16 half4v;
typedef __attribute__((ext_vector_type(4))) float float4v;

#define MFMAH(a, b, c) __builtin_amdgcn_mfma_f32_16x16x32_f16((a), (b), (c), 0, 0, 0)

// ---------------- prep: W frags + ranges + zero-init (absorbs both memsets) ----------------
// grid: 16 blocks x 256
__global__ __launch_bounds__(256) void k_prep(const float* __restrict__ W1,
                                              const float* __restrict__ W2,
                                              const int* __restrict__ batch,
                                              _Float16* __restrict__ wW1,
                                              _Float16* __restrict__ wW2,
                                              int* __restrict__ firstp,
                                              int* __restrict__ lastp,
                                              float* __restrict__ dout,
                                              float* __restrict__ ws) {
    int tid = blockIdx.x * 256 + threadIdx.x;   // 0..4095

    // zero dout pooled-out region (256 KB) : 4 float4 per thread
    float4 z4 = make_float4(0.f, 0.f, 0.f, 0.f);
#pragma unroll
    for (int i = 0; i < 4; ++i) ((float4*)dout)[tid + i * 4096] = z4;
    // zero ws entropy+stats (16 KB)
    ws[tid] = 0.f;

    if (tid < 8 * 4 * 64) {                       // W1: nt(8), ks(4), lane(64)
        int l = tid & 63, ks = (tid >> 6) & 3, nt = tid >> 8;
        int n = nt * 16 + (l & 15);
        int cb = ks * 32 + (l >> 4) * 8;
        half8 H;
#pragma unroll
        for (int j = 0; j < 8; ++j) H[j] = (_Float16)W1[(size_t)(cb + j) * CC + n];
        ((half8*)wW1)[(nt * 4 + ks) * 64 + l] = H;
    } else if (tid < 2048 + 512) {                // W2: nt(2), ks(4), lane(64)
        int t2 = tid - 2048;
        int l = t2 & 63, ks = (t2 >> 6) & 3, nt = t2 >> 8;
        int n = nt * 16 + (l & 15);
        int cb = ks * 32 + (l >> 4) * 8;
        half8 H;
#pragma unroll
        for (int j = 0; j < 8; ++j) H[j] = (_Float16)W2[(size_t)(cb + j) * KK + n];
        ((half8*)wW2)[(nt * 4 + ks) * 64 + l] = H;
    } else if (tid < 2560 + 16) {
        // full-tile range of graph b (graph 15's hi padded to NTILES*64)
        int b = tid - 2560;
        int lo = 0, hi = NN;
        while (lo < hi) { int mid = (lo + hi) >> 1; if (batch[mid] < b) lo = mid + 1; else hi = mid; }
        int lob = lo;
        lo = 0; hi = NN;
        while (lo < hi) { int mid = (lo + hi) >> 1; if (batch[mid] < b + 1) lo = mid + 1; else hi = mid; }
        int hib = (b == BG - 1) ? NTILES * 64 : lo;
        firstp[b] = (lob + 63) >> 6;
        lastp[b]  = (hib >> 6) - 1;
    }
}

// ---------------- fused single-tile: MLP (fp16 MFMA) + gumbel softmax + stats + pooling ----------------
// Post-barrier prefetch: gumbel u + W2 frags issued right after S1 (overlap GEMM1, drain at S2).
__global__ __launch_bounds__(256, 4) void k_assign(
    const float* __restrict__ x, const int* __restrict__ batch,
    const float* __restrict__ pos, const float* __restrict__ gum,
    const float* __restrict__ b1, const float* __restrict__ b2,
    const float* __restrict__ scaling, const float* __restrict__ amask,
    const _Float16* __restrict__ wW1, const _Float16* __restrict__ wW2,
    float* __restrict__ dout, float* __restrict__ ws,
    _Float16* __restrict__ part)
{
    __shared__ _Float16 xh[64][136];   // x fp16, live all kernel (pool B-source)
    __shared__ _Float16 hb[64][136];   // h fp16; dead after GEMM2 -> aliased as sbuf/pt
    __shared__ _Float16 st[32][72];    // s^T fp16 (pooling A + stats)
    __shared__ float lpx[64], lpy[64], lpsq[64];
    __shared__ int lbat[64];
    float* sbuf = (float*)&hb[0][0];             // [4 stats][8 ch][32 k] + [4] entropy partials
    _Float16* pt = (_Float16*)(sbuf + 1088);     // pool tile stage [32][128] fp16 (8 KB)

    const int t = threadIdx.x;
    const bool usep = (part != nullptr);
    // bijective XCD-chunked swizzle
    const int orig = blockIdx.x;
    const int qq = NTILES >> 3, rr8 = NTILES & 7;   // 195, 3
    const int xcd = orig & 7, sidx = orig >> 3;
    const int tile = (xcd < rr8 ? xcd * (qq + 1) : rr8 * (qq + 1) + (xcd - rr8) * qq) + sidx;
    const int n0 = tile * 64;

    const int l = t & 63;
    const int wv = __builtin_amdgcn_readfirstlane(t >> 6);
    const int li = l & 15;
    const int g16 = l >> 4;
    const int cc4 = (t & 31) * 4;
    const int nb = t >> 5;
    const int ca  = (2 * wv) * 16 + li;     // pooling c-col 0
    const int cb2 = (2 * wv + 1) * 16 + li; // pooling c-col 1
    const int sk = t & 31, sch = t >> 5;    // stats mapping

    const float scal = scaling[0];
    const float b2v0 = b2[li], b2v1 = b2[16 + li];
    const float am0 = amask[li], am1 = amask[16 + li];
    const float bv0 = b1[(2 * wv) * 16 + li];
    const float bv1 = b1[(2 * wv + 1) * 16 + li];

    // ---- stage x -> fp16 LDS (coalesced float4) ----
#pragma unroll
    for (int r = 0; r < 8; ++r) {
        int n = r * 8 + nb;
        int gn = n0 + n;
        float4 v = make_float4(0.f, 0.f, 0.f, 0.f);
        if (gn < NN) v = *(const float4*)(x + (size_t)gn * CC + cc4);
        *(half4v*)&xh[n][cc4] =
            (half4v){(_Float16)v.x, (_Float16)v.y, (_Float16)v.z, (_Float16)v.w};
    }
    if (t < 64) {
        int gn = n0 + t;
        float px = 0.f, py = 0.f; int bb = BG - 1;
        if (gn < NN) { px = pos[gn * 2]; py = pos[gn * 2 + 1]; bb = batch[gn]; }
        lpx[t] = px; lpy[t] = py; lpsq[t] = px * px + py * py; lbat[t] = bb;
    }
    __syncthreads();   // S1: x tile + meta staged

    // ---- post-barrier prefetch: gumbel u + W2 frags (fly during GEMM1, drain at S2) ----
    float ur[8];
#pragma unroll
    for (int r2 = 0; r2 < 4; ++r2) {
        int gn = n0 + wv * 16 + g16 * 4 + r2;
        bool valid = gn < NN;
        ur[r2 * 2]     = valid ? gum[(size_t)gn * KK + li]      : 0.5f;
        ur[r2 * 2 + 1] = valid ? gum[(size_t)gn * KK + 16 + li] : 0.5f;
    }
    const half8* W2B = (const half8*)wW2;
    half8 w2r0[4], w2r1[4];
#pragma unroll
    for (int ks = 0; ks < 4; ++ks) {
        w2r0[ks] = W2B[(0 * 4 + ks) * 64 + l];
        w2r1[ks] = W2B[(1 * 4 + ks) * 64 + l];
    }

    // ---- GEMM1: h = x @ W1 ----
    float4v acc[4][2];
#pragma unroll
    for (int mt = 0; mt < 4; ++mt) {
        acc[mt][0] = (float4v){0.f, 0.f, 0.f, 0.f};
        acc[mt][1] = (float4v){0.f, 0.f, 0.f, 0.f};
    }
    const half8* W1B = (const half8*)wW1;
#pragma unroll
    for (int ks = 0; ks < 4; ++ks) {
        half8 bh0 = W1B[((2 * wv    ) * 4 + ks) * 64 + l];
        half8 bh1 = W1B[((2 * wv + 1) * 4 + ks) * 64 + l];
#pragma unroll
        for (int mt = 0; mt < 4; ++mt) {
            half8 ah = *(const half8*)&xh[mt * 16 + li][ks * 32 + g16 * 8];
            acc[mt][0] = MFMAH(ah, bh0, acc[mt][0]);
            acc[mt][1] = MFMAH(ah, bh1, acc[mt][1]);
        }
    }

    // ---- h = relu(acc + b1) -> hb ----
#pragma unroll
    for (int mt = 0; mt < 4; ++mt) {
#pragma unroll
        for (int r2 = 0; r2 < 4; ++r2) {
            int row = mt * 16 + g16 * 4 + r2;
            hb[row][(2 * wv) * 16 + li]     = (_Float16)fmaxf(acc[mt][0][r2] + bv0, 0.f);
            hb[row][(2 * wv + 1) * 16 + li] = (_Float16)fmaxf(acc[mt][1][r2] + bv1, 0.f);
        }
    }
    __syncthreads();   // S2: h visible; prefetched ur/w2r complete by now

    // ---- GEMM2: logits = h @ W2 (frags already in regs) ----
    float4v acc2[2];
    acc2[0] = (float4v){0.f, 0.f, 0.f, 0.f};
    acc2[1] = (float4v){0.f, 0.f, 0.f, 0.f};
#pragma unroll
    for (int ks = 0; ks < 4; ++ks) {
        half8 ah = *(const half8*)&hb[wv * 16 + li][ks * 32 + g16 * 8];
        acc2[0] = MFMAH(ah, w2r0[ks], acc2[0]);
        acc2[1] = MFMAH(ah, w2r1[ks], acc2[1]);
    }

    // ---- softmax (no max-subtraction: |z| bounded << 88); s kept in regs, stored at END ----
    float ep_acc = 0.f;
    float sr0[4], sr1[4];
#pragma unroll
    for (int r2 = 0; r2 < 4; ++r2) {
        int m = wv * 16 + g16 * 4 + r2;
        int gn = n0 + m;
        bool valid = gn < NN;
        float lg0 = (acc2[0][r2] + b2v0) * scal; if (am0 == 0.f) lg0 = -1e9f;
        float lg1 = (acc2[1][r2] + b2v1) * scal; if (am1 == 0.f) lg1 = -1e9f;
        float z0 = lg0 - __logf(-__logf(ur[r2 * 2] + EPSF) + EPSF);
        float z1 = lg1 - __logf(-__logf(ur[r2 * 2 + 1] + EPSF) + EPSF);
        float e0 = __expf(z0), e1 = __expf(z1);
        float sm = e0 + e1;
        sm += __shfl_xor(sm, 1);
        sm += __shfl_xor(sm, 2);
        sm += __shfl_xor(sm, 4);
        sm += __shfl_xor(sm, 8);
        float inv = 1.f / sm;
        float s0 = e0 * inv, s1 = e1 * inv;
        if (!valid) { s0 = 0.f; s1 = 0.f; }
        sr0[r2] = s0; sr1[r2] = s1;
        st[li][m] = (_Float16)s0;
        st[16 + li][m] = (_Float16)s1;
        ep_acc += s0 * __logf(s0 + EPSF) + s1 * __logf(s1 + EPSF);
    }
    __syncthreads();   // S3: st ready; hb dead (sbuf/pt alias it)

    // ---- entropy: wave-reduce -> LDS partials ----
    ep_acc += __shfl_xor(ep_acc, 1);
    ep_acc += __shfl_xor(ep_acc, 2);
    ep_acc += __shfl_xor(ep_acc, 4);
    ep_acc += __shfl_xor(ep_acc, 8);
    ep_acc += __shfl_xor(ep_acc, 16);
    ep_acc += __shfl_xor(ep_acc, 32);
    if (l == 0) sbuf[1024 + wv] = ep_acc;

    // ---- segment geometry ----
    const int b0 = lbat[0], b63 = lbat[63];
    int cut = 64;
    if (b0 != b63) {
        for (int i = 1; i < 64; ++i) { if (lbat[i] != b0) { cut = i; break; } }
    }
    const int nseg = (b0 == b63) ? 1 : 2;

    // ---- stats: per-thread partials -> LDS -> 128 atomics per segment ----
#pragma unroll 1
    for (int sg = 0; sg < nseg; ++sg) {
        const int lo = sg ? cut : 0;
        const int hi = sg ? 64 : cut;
        const int bb = sg ? b63 : b0;
        float prs = 0.f, ppx = 0.f, ppy = 0.f, psq = 0.f;
#pragma unroll
        for (int r = 0; r < 8; ++r) {
            int n = sch * 8 + r;
            if (n >= lo && n < hi) {
                float sv = (float)st[sk][n];
                prs += sv; ppx += sv * lpx[n]; ppy += sv * lpy[n]; psq += sv * lpsq[n];
            }
        }
        if (sg) __syncthreads();
        sbuf[(0 * 8 + sch) * 32 + sk] = prs;
        sbuf[(1 * 8 + sch) * 32 + sk] = ppx;
        sbuf[(2 * 8 + sch) * 32 + sk] = ppy;
        sbuf[(3 * 8 + sch) * 32 + sk] = psq;
        __syncthreads();
        if (t < 128) {
            int stat = t >> 5, k = t & 31;
            float a = 0.f;
#pragma unroll
            for (int c = 0; c < 8; ++c) a += sbuf[(stat * 8 + c) * 32 + k];
            atomicAdd(ws + WS_STAT + stat * 512 + bb * KK + k, a);
        }
    }

    // ---- entropy partial: one plain store per block ----
    if (t == 0) {
        ws[WS_ENTARR + orig] = sbuf[1024] + sbuf[1025] + sbuf[1026] + sbuf[1027];
    }

    // ---- pooling: s^T x via MFMA (x frags read from still-live xh) ----
    float4v p00 = {0.f, 0.f, 0.f, 0.f}, p01 = p00, p10 = p00, p11 = p00;
    auto pool_flush = [&](int bb) {
        float* ob = dout + (size_t)bb * KK * CC;
#pragma unroll
        for (int r2 = 0; r2 < 4; ++r2) {
            int k0r = g16 * 4 + r2;
            atomicAdd(ob + k0r * CC + ca, p00[r2]);
            atomicAdd(ob + k0r * CC + cb2, p01[r2]);
            atomicAdd(ob + (16 + k0r) * CC + ca, p10[r2]);
            atomicAdd(ob + (16 + k0r) * CC + cb2, p11[r2]);
        }
        p00 = (float4v){0.f, 0.f, 0.f, 0.f}; p01 = p00; p10 = p00; p11 = p00;
    };
    if (b0 == b63) {
#pragma unroll
        for (int ksl = 0; ksl < 2; ++ksl) {
            half8 a0 = *(const half8*)&st[li][ksl * 32 + g16 * 8];
            half8 a1 = *(const half8*)&st[16 + li][ksl * 32 + g16 * 8];
            half8 v0, v1;
#pragma unroll
            for (int j = 0; j < 8; ++j) {
                int i = ksl * 32 + g16 * 8 + j;
                v0[j] = xh[i][ca];
                v1[j] = xh[i][cb2];
            }
            p00 = MFMAH(a0, v0, p00);
            p01 = MFMAH(a0, v1, p01);
            p10 = MFMAH(a1, v0, p10);
            p11 = MFMAH(a1, v1, p11);
        }
        if (usep) {
            // stage tile in LDS (fp16), then fully-coalesced 16B/lane writes
#pragma unroll
            for (int r2 = 0; r2 < 4; ++r2) {
                int k0r = g16 * 4 + r2;
                pt[k0r * CC + ca]         = (_Float16)p00[r2];
                pt[k0r * CC + cb2]        = (_Float16)p01[r2];
                pt[(16 + k0r) * CC + ca]  = (_Float16)p10[r2];
                pt[(16 + k0r) * CC + cb2] = (_Float16)p11[r2];
            }
            __syncthreads();   // S4 (block-uniform path)
            _Float16* pb = part + (size_t)tile * 4096 + t * 16;
            const _Float16* src = pt + t * 16;
            *(half8*)(pb)     = *(const half8*)(src);
            *(half8*)(pb + 8) = *(const half8*)(src + 8);
        } else {
            pool_flush(b0);
        }
    } else {
#pragma unroll 1
        for (int pass = 0; pass < 2; ++pass) {
            int lo = pass ? cut : 0;
            int hi = pass ? 64 : cut;
            int bb = pass ? b63 : b0;
#pragma unroll
            for (int ksl = 0; ksl < 2; ++ksl) {
                half8 a0, a1, v0, v1;
#pragma unroll
                for (int j = 0; j < 8; ++j) {
                    int i = ksl * 32 + g16 * 8 + j;
                    bool in = (i >= lo) && (i < hi);
                    a0[j] = in ? st[li][i] : (_Float16)0.f;
                    a1[j] = in ? st[16 + li][i] : (_Float16)0.f;
                    v0[j] = xh[i][ca];
                    v1[j] = xh[i][cb2];
                }
                p00 = MFMAH(a0, v0, p00);
                p01 = MFMAH(a0, v1, p01);
                p10 = MFMAH(a1, v0, p10);
                p11 = MFMAH(a1, v1, p11);
            }
            pool_flush(bb);
        }
    }

    // ---- deferred s stores (overlap; drain at endpgm) ----
#pragma unroll
    for (int r2 = 0; r2 < 4; ++r2) {
        int gn = n0 + wv * 16 + g16 * 4 + r2;
        if (gn < NN) {
            dout[S_OFF + (size_t)gn * KK + li]      = sr0[r2];
            dout[S_OFF + (size_t)gn * KK + 16 + li] = sr1[r2];
        }
    }
}

// ---------------- reduce pool partials into out + merged finalize ----------------
// grid: BG*16*8 + 1 blocks; last block computes losses/centroids
__global__ __launch_bounds__(256) void k_reduce(const _Float16* __restrict__ part,
                                                const int* __restrict__ firstp,
                                                const int* __restrict__ lastp,
                                                const float* __restrict__ ws,
                                                const float* __restrict__ amask,
                                                float* __restrict__ dout) {
    if (blockIdx.x < BG * 16 * 8) {
        if (part == nullptr) return;
        const int b   = blockIdx.x >> 7;
        const int elc = (blockIdx.x >> 3) & 15;
        const int sp  = blockIdx.x & 7;
        const int el  = elc * 256 + threadIdx.x;   // k*128+c
        const int lo = firstp[b], hi = lastp[b];
        if (lo > hi) return;
        const int count = hi - lo + 1;
        const int per = (count + 7) >> 3;
        const int t0 = lo + sp * per;
        if (t0 > hi) return;
        int t1 = t0 + per - 1; if (t1 > hi) t1 = hi;
        float s0 = 0.f, s1 = 0.f;
        int tt = t0;
        for (; tt + 1 <= t1; tt += 2) {
            s0 += (float)part[(size_t)tt * 4096 + el];
            s1 += (float)part[(size_t)(tt + 1) * 4096 + el];
        }
        if (tt <= t1) s0 += (float)part[(size_t)tt * 4096 + el];
        atomicAdd(dout + (size_t)b * 4096 + el, s0 + s1);
        return;
    }

    // ---- finalize losses + centroids (single block) ----
    __shared__ float avg[32], csum[32], cpx[32], cpy[32], csq[32];
    __shared__ float lmu[16][32][2];
    __shared__ float red[4], ered[4];
    const int t = threadIdx.x;

    float esum = 0.f;
    for (int i = t; i < NTILES; i += 256) esum += ws[WS_ENTARR + i];
    esum += __shfl_xor(esum, 1);
    esum += __shfl_xor(esum, 2);
    esum += __shfl_xor(esum, 4);
    esum += __shfl_xor(esum, 8);
    esum += __shfl_xor(esum, 16);
    esum += __shfl_xor(esum, 32);
    if ((t & 63) == 0) ered[t >> 6] = esum;

    if (t < 32) {
        float a = 0.f, px = 0.f, py = 0.f, sq = 0.f;
        for (int b = 0; b < BG; ++b) {
            a  += ws[WS_STAT + 0 * 512 + b * KK + t];
            px += ws[WS_STAT + 1 * 512 + b * KK + t];
            py += ws[WS_STAT + 2 * 512 + b * KK + t];
            sq += ws[WS_STAT + 3 * 512 + b * KK + t];
        }
        csum[t] = a; cpx[t] = px; cpy[t] = py; csq[t] = sq;
        avg[t] = a / (float)NN;
    }
    for (int idx = t; idx < BG * KK; idx += 256) {
        float den = ws[WS_STAT + idx] + EPSF;
        float mx = ws[WS_STAT + 512 + idx] / den;
        float my = ws[WS_STAT + 1024 + idx] / den;
        int b = idx >> 5, k = idx & 31;
        lmu[b][k][0] = mx; lmu[b][k][1] = my;
        dout[MU_OFF + idx * 2] = mx;
        dout[MU_OFF + idx * 2 + 1] = my;
    }
    __syncthreads();
    float sep = 0.f;
    for (int idx = t; idx < BG * KK * KK; idx += 256) {
        int b = idx >> 10, k1 = (idx >> 5) & 31, k2 = idx & 31;
        if (k1 != k2) {
            float dx = lmu[b][k1][0] - lmu[b][k2][0];
            float dy = lmu[b][k1][1] - lmu[b][k2][1];
            sep += 1.f / (dx * dx + dy * dy + 1.f);
        }
    }
    for (int off = 32; off; off >>= 1) sep += __shfl_down(sep, off);
    if ((t & 63) == 0) red[t >> 6] = sep;
    __syncthreads();
    if (t == 0) {
        float sept = red[0] + red[1] + red[2] + red[3];
        float separation = sept / ((float)(KK * (KK - 1)) + EPSF);
        float entropy = -(ered[0] + ered[1] + ered[2] + ered[3]) / (float)NN;
        float diversity = 0.f, pruning = 0.f, msum = 0.f, entavg = 0.f, bal = 0.f, mxa = 0.f, spatial = 0.f;
        const float up = 1.f / (float)KK;
        for (int k = 0; k < KK; ++k) {
            float a = avg[k];
            diversity += up * logf(up / (a + EPSF));
            float mk = amask[k];
            pruning += fabsf(a * (1.f - mk));
            msum += mk;
            entavg -= a * logf(a + EPSF);
            bal += a * logf(a * (float)KK + EPSF);
            mxa = fmaxf(mxa, a);
            float den = csum[k] + EPSF;
            float mux = cpx[k] / den, muy = cpy[k] / den;
            spatial += csq[k] / den - (mux * mux + muy * muy);
        }
        pruning *= up;
        spatial *= up;
        const float lk = logf((float)KK);
        float collapse = ((lk - entavg) / lk + fmaxf(mxa - 2.f / (float)KK, 0.f)) * 2.0f;
        float sparsity = (msum / (float)KK) * 0.01f;
        dout[LOSS_OFF + 0] = entropy;
        dout[LOSS_OFF + 1] = diversity;
        dout[LOSS_OFF + 2] = spatial;
        dout[LOSS_OFF + 3] = pruning;
        dout[LOSS_OFF + 4] = sparsity;
        dout[LOSS_OFF + 5] = 0.f;
        dout[LOSS_OFF + 6] = collapse;
        dout[LOSS_OFF + 7] = bal;
        dout[LOSS_OFF + 8] = separation;
    }
}

extern "C" void kernel_launch(void* const* d_in, const int* in_sizes, int n_in,
                              void* d_out, int out_size, void* d_ws, size_t ws_size,
                              hipStream_t stream) {
    const float* x     = (const float*)d_in[0];
    const int*   batch = (const int*)d_in[1];
    const float* pos   = (const float*)d_in[2];
    const float* gum   = (const float*)d_in[3];
    const float* W1    = (const float*)d_in[4];
    const float* b1    = (const float*)d_in[5];
    const float* W2    = (const float*)d_in[6];
    const float* b2    = (const float*)d_in[7];
    const float* scal  = (const float*)d_in[8];
    const float* amask = (const float*)d_in[9];
    float* dout = (float*)d_out;
    float* ws   = (float*)d_ws;
    _Float16* wW1 = (_Float16*)((char*)d_ws + W1B_OFF_BYTES);
    _Float16* wW2 = (_Float16*)((char*)d_ws + W2B_OFF_BYTES);
    int* firstp = (int*)(ws + WS_FIRST);
    int* lastp  = (int*)(ws + WS_LAST);
    const bool usep = (ws_size >= (size_t)WS_NEEDED_BYTES);
    _Float16* partp = usep ? (_Float16*)((char*)d_ws + WS_PART_BYTE) : nullptr;

    k_prep<<<16, 256, 0, stream>>>(W1, W2, batch, wW1, wW2, firstp, lastp, dout, ws);
    k_assign<<<NTILES, 256, 0, stream>>>(x, batch, pos, gum, b1, b2,
                                         scal, amask, wW1, wW2, dout, ws, partp);
    k_reduce<<<BG * 16 * 8 + 1, 256, 0, stream>>>(partp, firstp, lastp, ws, amask, dout);
}

// Round 22
// 69.620 us; speedup vs baseline: 1.0551x; 1.0179x over previous
//
#include <hip/hip_runtime.h>
#include <math.h>

#define NN 100000
#define CC 128
#define KK 32
#define BG 16
#define EPSF 1e-9f

#define NTILES 1563   // ceil(NN/64)

// d_out float layout: out[16][32][128] | s[100000][32] | mu[16][32][2] | losses[9]
#define S_OFF 65536
#define MU_OFF 3265536
#define LOSS_OFF 3266560

// ws float layout:
//   [0 .. 2048)      per-block entropy partials (plain stores)
//   [2048 .. 4096)   stats [4 stats][16 b][32 k]
//   [4096 .. 4112)   first-full-tile[b] (int)
//   [4112 .. 4128)   last-full-tile[b]  (int)
//   byte 16896: W1 frags (32 KB); byte 49664: W2 frags (8 KB)
//   byte 65536: pool partials [NTILES][32][128] fp16 (12.8 MB, if ws fits)
#define WS_ENTARR 0
#define WS_STAT 2048
#define WS_FIRST 4096
#define WS_LAST 4112

#define W1B_OFF_BYTES 16896
#define W2B_OFF_BYTES 49664
#define WS_PART_BYTE 65536
#define WS_NEEDED_BYTES (65536ull + (unsigned long long)NTILES * 4096ull * 2ull)

typedef __attribute__((ext_vector_type(8))) _Float16 half8;
typedef __attribute__((ext_vector_type(4))) _Float16 half4v;
typedef __attribute__((ext_vector_type(4))) float float4v;

#define MFMAH(a, b, c) __builtin_amdgcn_mfma_f32_16x16x32_f16((a), (b), (c), 0, 0, 0)

// ---------------- prep: W frags + ranges + zero-init (absorbs both memsets) ----------------
// grid: 16 blocks x 256
__global__ __launch_bounds__(256) void k_prep(const float* __restrict__ W1,
                                              const float* __restrict__ W2,
                                              const int* __restrict__ batch,
                                              _Float16* __restrict__ wW1,
                                              _Float16* __restrict__ wW2,
                                              int* __restrict__ firstp,
                                              int* __restrict__ lastp,
                                              float* __restrict__ dout,
                                              float* __restrict__ ws) {
    int tid = blockIdx.x * 256 + threadIdx.x;   // 0..4095

    // zero dout pooled-out region (256 KB) : 4 float4 per thread
    float4 z4 = make_float4(0.f, 0.f, 0.f, 0.f);
#pragma unroll
    for (int i = 0; i < 4; ++i) ((float4*)dout)[tid + i * 4096] = z4;
    // zero ws entropy+stats (16 KB)
    ws[tid] = 0.f;

    if (tid < 8 * 4 * 64) {                       // W1: nt(8), ks(4), lane(64)
        int l = tid & 63, ks = (tid >> 6) & 3, nt = tid >> 8;
        int n = nt * 16 + (l & 15);
        int cb = ks * 32 + (l >> 4) * 8;
        half8 H;
#pragma unroll
        for (int j = 0; j < 8; ++j) H[j] = (_Float16)W1[(size_t)(cb + j) * CC + n];
        ((half8*)wW1)[(nt * 4 + ks) * 64 + l] = H;
    } else if (tid < 2048 + 512) {                // W2: nt(2), ks(4), lane(64)
        int t2 = tid - 2048;
        int l = t2 & 63, ks = (t2 >> 6) & 3, nt = t2 >> 8;
        int n = nt * 16 + (l & 15);
        int cb = ks * 32 + (l >> 4) * 8;
        half8 H;
#pragma unroll
        for (int j = 0; j < 8; ++j) H[j] = (_Float16)W2[(size_t)(cb + j) * KK + n];
        ((half8*)wW2)[(nt * 4 + ks) * 64 + l] = H;
    } else if (tid < 2560 + 16) {
        // full-tile range of graph b (graph 15's hi padded to NTILES*64)
        int b = tid - 2560;
        int lo = 0, hi = NN;
        while (lo < hi) { int mid = (lo + hi) >> 1; if (batch[mid] < b) lo = mid + 1; else hi = mid; }
        int lob = lo;
        lo = 0; hi = NN;
        while (lo < hi) { int mid = (lo + hi) >> 1; if (batch[mid] < b + 1) lo = mid + 1; else hi = mid; }
        int hib = (b == BG - 1) ? NTILES * 64 : lo;
        firstp[b] = (lob + 63) >> 6;
        lastp[b]  = (hib >> 6) - 1;
    }
}

// ---------------- fused single-tile: MLP (fp16 MFMA) + gumbel softmax + stats + pooling ----------------
// 3-4 barriers; pool tile staged in LDS then written as full-line fp16; s-stores deferred.
__global__ __launch_bounds__(256, 4) void k_assign(
    const float* __restrict__ x, const int* __restrict__ batch,
    const float* __restrict__ pos, const float* __restrict__ gum,
    const float* __restrict__ b1, const float* __restrict__ b2,
    const float* __restrict__ scaling, const float* __restrict__ amask,
    const _Float16* __restrict__ wW1, const _Float16* __restrict__ wW2,
    float* __restrict__ dout, float* __restrict__ ws,
    _Float16* __restrict__ part)
{
    __shared__ _Float16 xh[64][136];   // x fp16, live all kernel (pool B-source)
    __shared__ _Float16 hb[64][136];   // h fp16; dead after GEMM2 -> aliased as sbuf/pt
    __shared__ _Float16 st[32][72];    // s^T fp16 (pooling A + stats)
    __shared__ float lpx[64], lpy[64], lpsq[64];
    __shared__ int lbat[64];
    float* sbuf = (float*)&hb[0][0];             // [4 stats][8 ch][32 k] + [4] entropy partials
    _Float16* pt = (_Float16*)(sbuf + 1088);     // pool tile stage [32][128] fp16 (8 KB)

    const int t = threadIdx.x;
    const bool usep = (part != nullptr);
    // bijective XCD-chunked swizzle
    const int orig = blockIdx.x;
    const int qq = NTILES >> 3, rr8 = NTILES & 7;   // 195, 3
    const int xcd = orig & 7, sidx = orig >> 3;
    const int tile = (xcd < rr8 ? xcd * (qq + 1) : rr8 * (qq + 1) + (xcd - rr8) * qq) + sidx;
    const int n0 = tile * 64;

    const int l = t & 63;
    const int wv = __builtin_amdgcn_readfirstlane(t >> 6);
    const int li = l & 15;
    const int g16 = l >> 4;
    const int cc4 = (t & 31) * 4;
    const int nb = t >> 5;
    const int ca  = (2 * wv) * 16 + li;     // pooling c-col 0
    const int cb2 = (2 * wv + 1) * 16 + li; // pooling c-col 1
    const int sk = t & 31, sch = t >> 5;    // stats mapping

    const float scal = scaling[0];
    const float b2v0 = b2[li], b2v1 = b2[16 + li];
    const float am0 = amask[li], am1 = amask[16 + li];
    const float bv0 = b1[(2 * wv) * 16 + li];
    const float bv1 = b1[(2 * wv + 1) * 16 + li];

    // ---- stage x -> fp16 LDS (coalesced float4) ----
#pragma unroll
    for (int r = 0; r < 8; ++r) {
        int n = r * 8 + nb;
        int gn = n0 + n;
        float4 v = make_float4(0.f, 0.f, 0.f, 0.f);
        if (gn < NN) v = *(const float4*)(x + (size_t)gn * CC + cc4);
        *(half4v*)&xh[n][cc4] =
            (half4v){(_Float16)v.x, (_Float16)v.y, (_Float16)v.z, (_Float16)v.w};
    }
    if (t < 64) {
        int gn = n0 + t;
        float px = 0.f, py = 0.f; int bb = BG - 1;
        if (gn < NN) { px = pos[gn * 2]; py = pos[gn * 2 + 1]; bb = batch[gn]; }
        lpx[t] = px; lpy[t] = py; lpsq[t] = px * px + py * py; lbat[t] = bb;
    }

    // ---- gumbel loads (drained at S1 regardless; issue here for address reuse) ----
    float gu[8];
#pragma unroll
    for (int r2 = 0; r2 < 4; ++r2) {
        int gn = n0 + wv * 16 + g16 * 4 + r2;
        bool valid = gn < NN;
        gu[r2 * 2]     = valid ? gum[(size_t)gn * KK + li]      : 0.5f;
        gu[r2 * 2 + 1] = valid ? gum[(size_t)gn * KK + 16 + li] : 0.5f;
    }
    __syncthreads();   // S1: x tile + meta staged

    // ---- GEMM1: h = x @ W1 ----
    float4v acc[4][2];
#pragma unroll
    for (int mt = 0; mt < 4; ++mt) {
        acc[mt][0] = (float4v){0.f, 0.f, 0.f, 0.f};
        acc[mt][1] = (float4v){0.f, 0.f, 0.f, 0.f};
    }
    const half8* W1B = (const half8*)wW1;
#pragma unroll
    for (int ks = 0; ks < 4; ++ks) {
        half8 bh0 = W1B[((2 * wv    ) * 4 + ks) * 64 + l];
        half8 bh1 = W1B[((2 * wv + 1) * 4 + ks) * 64 + l];
#pragma unroll
        for (int mt = 0; mt < 4; ++mt) {
            half8 ah = *(const half8*)&xh[mt * 16 + li][ks * 32 + g16 * 8];
            acc[mt][0] = MFMAH(ah, bh0, acc[mt][0]);
            acc[mt][1] = MFMAH(ah, bh1, acc[mt][1]);
        }
    }

    // ---- h = relu(acc + b1) -> hb ----
#pragma unroll
    for (int mt = 0; mt < 4; ++mt) {
#pragma unroll
        for (int r2 = 0; r2 < 4; ++r2) {
            int row = mt * 16 + g16 * 4 + r2;
            hb[row][(2 * wv) * 16 + li]     = (_Float16)fmaxf(acc[mt][0][r2] + bv0, 0.f);
            hb[row][(2 * wv + 1) * 16 + li] = (_Float16)fmaxf(acc[mt][1][r2] + bv1, 0.f);
        }
    }
    __syncthreads();   // S2: h visible to all waves

    // ---- GEMM2: logits = h @ W2 ----
    float4v acc2[2];
    acc2[0] = (float4v){0.f, 0.f, 0.f, 0.f};
    acc2[1] = (float4v){0.f, 0.f, 0.f, 0.f};
    const half8* W2B = (const half8*)wW2;
#pragma unroll
    for (int ks = 0; ks < 4; ++ks) {
        half8 ah = *(const half8*)&hb[wv * 16 + li][ks * 32 + g16 * 8];
        acc2[0] = MFMAH(ah, W2B[(0 * 4 + ks) * 64 + l], acc2[0]);
        acc2[1] = MFMAH(ah, W2B[(1 * 4 + ks) * 64 + l], acc2[1]);
    }

    // ---- softmax (no max-subtraction: |z| bounded << 88); s kept in regs, stored at END ----
    float ep_acc = 0.f;
    float sr0[4], sr1[4];
#pragma unroll
    for (int r2 = 0; r2 < 4; ++r2) {
        int m = wv * 16 + g16 * 4 + r2;
        int gn = n0 + m;
        bool valid = gn < NN;
        float lg0 = (acc2[0][r2] + b2v0) * scal; if (am0 == 0.f) lg0 = -1e9f;
        float lg1 = (acc2[1][r2] + b2v1) * scal; if (am1 == 0.f) lg1 = -1e9f;
        float z0 = lg0 - __logf(-__logf(gu[r2 * 2] + EPSF) + EPSF);
        float z1 = lg1 - __logf(-__logf(gu[r2 * 2 + 1] + EPSF) + EPSF);
        float e0 = __expf(z0), e1 = __expf(z1);
        float sm = e0 + e1;
        sm += __shfl_xor(sm, 1);
        sm += __shfl_xor(sm, 2);
        sm += __shfl_xor(sm, 4);
        sm += __shfl_xor(sm, 8);
        float inv = 1.f / sm;
        float s0 = e0 * inv, s1 = e1 * inv;
        if (!valid) { s0 = 0.f; s1 = 0.f; }
        sr0[r2] = s0; sr1[r2] = s1;
        st[li][m] = (_Float16)s0;
        st[16 + li][m] = (_Float16)s1;
        ep_acc += s0 * __logf(s0 + EPSF) + s1 * __logf(s1 + EPSF);
    }
    __syncthreads();   // S3: st ready; hb dead (sbuf/pt alias it)

    // ---- entropy: wave-reduce -> LDS partials ----
    ep_acc += __shfl_xor(ep_acc, 1);
    ep_acc += __shfl_xor(ep_acc, 2);
    ep_acc += __shfl_xor(ep_acc, 4);
    ep_acc += __shfl_xor(ep_acc, 8);
    ep_acc += __shfl_xor(ep_acc, 16);
    ep_acc += __shfl_xor(ep_acc, 32);
    if (l == 0) sbuf[1024 + wv] = ep_acc;

    // ---- segment geometry ----
    const int b0 = lbat[0], b63 = lbat[63];
    int cut = 64;
    if (b0 != b63) {
        for (int i = 1; i < 64; ++i) { if (lbat[i] != b0) { cut = i; break; } }
    }
    const int nseg = (b0 == b63) ? 1 : 2;

    // ---- stats: per-thread partials -> LDS -> 128 atomics per segment ----
#pragma unroll 1
    for (int sg = 0; sg < nseg; ++sg) {
        const int lo = sg ? cut : 0;
        const int hi = sg ? 64 : cut;
        const int bb = sg ? b63 : b0;
        float prs = 0.f, ppx = 0.f, ppy = 0.f, psq = 0.f;
#pragma unroll
        for (int r = 0; r < 8; ++r) {
            int n = sch * 8 + r;
            if (n >= lo && n < hi) {
                float sv = (float)st[sk][n];
                prs += sv; ppx += sv * lpx[n]; ppy += sv * lpy[n]; psq += sv * lpsq[n];
            }
        }
        if (sg) __syncthreads();
        sbuf[(0 * 8 + sch) * 32 + sk] = prs;
        sbuf[(1 * 8 + sch) * 32 + sk] = ppx;
        sbuf[(2 * 8 + sch) * 32 + sk] = ppy;
        sbuf[(3 * 8 + sch) * 32 + sk] = psq;
        __syncthreads();
        if (t < 128) {
            int stat = t >> 5, k = t & 31;
            float a = 0.f;
#pragma unroll
            for (int c = 0; c < 8; ++c) a += sbuf[(stat * 8 + c) * 32 + k];
            atomicAdd(ws + WS_STAT + stat * 512 + bb * KK + k, a);
        }
    }

    // ---- entropy partial: one plain store per block ----
    if (t == 0) {
        ws[WS_ENTARR + orig] = sbuf[1024] + sbuf[1025] + sbuf[1026] + sbuf[1027];
    }

    // ---- pooling: s^T x via MFMA (x frags read from still-live xh) ----
    float4v p00 = {0.f, 0.f, 0.f, 0.f}, p01 = p00, p10 = p00, p11 = p00;
    auto pool_flush = [&](int bb) {
        float* ob = dout + (size_t)bb * KK * CC;
#pragma unroll
        for (int r2 = 0; r2 < 4; ++r2) {
            int k0r = g16 * 4 + r2;
            atomicAdd(ob + k0r * CC + ca, p00[r2]);
            atomicAdd(ob + k0r * CC + cb2, p01[r2]);
            atomicAdd(ob + (16 + k0r) * CC + ca, p10[r2]);
            atomicAdd(ob + (16 + k0r) * CC + cb2, p11[r2]);
        }
        p00 = (float4v){0.f, 0.f, 0.f, 0.f}; p01 = p00; p10 = p00; p11 = p00;
    };
    if (b0 == b63) {
#pragma unroll
        for (int ksl = 0; ksl < 2; ++ksl) {
            half8 a0 = *(const half8*)&st[li][ksl * 32 + g16 * 8];
            half8 a1 = *(const half8*)&st[16 + li][ksl * 32 + g16 * 8];
            half8 v0, v1;
#pragma unroll
            for (int j = 0; j < 8; ++j) {
                int i = ksl * 32 + g16 * 8 + j;
                v0[j] = xh[i][ca];
                v1[j] = xh[i][cb2];
            }
            p00 = MFMAH(a0, v0, p00);
            p01 = MFMAH(a0, v1, p01);
            p10 = MFMAH(a1, v0, p10);
            p11 = MFMAH(a1, v1, p11);
        }
        if (usep) {
            // stage tile in LDS (fp16), then fully-coalesced 16B/lane writes
#pragma unroll
            for (int r2 = 0; r2 < 4; ++r2) {
                int k0r = g16 * 4 + r2;
                pt[k0r * CC + ca]         = (_Float16)p00[r2];
                pt[k0r * CC + cb2]        = (_Float16)p01[r2];
                pt[(16 + k0r) * CC + ca]  = (_Float16)p10[r2];
                pt[(16 + k0r) * CC + cb2] = (_Float16)p11[r2];
            }
            __syncthreads();   // S4 (block-uniform path)
            _Float16* pb = part + (size_t)tile * 4096 + t * 16;
            const _Float16* src = pt + t * 16;
            *(half8*)(pb)     = *(const half8*)(src);
            *(half8*)(pb + 8) = *(const half8*)(src + 8);
        } else {
            pool_flush(b0);
        }
    } else {
#pragma unroll 1
        for (int pass = 0; pass < 2; ++pass) {
            int lo = pass ? cut : 0;
            int hi = pass ? 64 : cut;
            int bb = pass ? b63 : b0;
#pragma unroll
            for (int ksl = 0; ksl < 2; ++ksl) {
                half8 a0, a1, v0, v1;
#pragma unroll
                for (int j = 0; j < 8; ++j) {
                    int i = ksl * 32 + g16 * 8 + j;
                    bool in = (i >= lo) && (i < hi);
                    a0[j] = in ? st[li][i] : (_Float16)0.f;
                    a1[j] = in ? st[16 + li][i] : (_Float16)0.f;
                    v0[j] = xh[i][ca];
                    v1[j] = xh[i][cb2];
                }
                p00 = MFMAH(a0, v0, p00);
                p01 = MFMAH(a0, v1, p01);
                p10 = MFMAH(a1, v0, p10);
                p11 = MFMAH(a1, v1, p11);
            }
            pool_flush(bb);
        }
    }

    // ---- deferred s stores (overlap; drain at endpgm) ----
#pragma unroll
    for (int r2 = 0; r2 < 4; ++r2) {
        int gn = n0 + wv * 16 + g16 * 4 + r2;
        if (gn < NN) {
            dout[S_OFF + (size_t)gn * KK + li]      = sr0[r2];
            dout[S_OFF + (size_t)gn * KK + 16 + li] = sr1[r2];
        }
    }
}

// ---------------- reduce pool partials into out + merged finalize ----------------
// grid: BG*16*8 + 1 blocks; last block computes losses/centroids
__global__ __launch_bounds__(256) void k_reduce(const _Float16* __restrict__ part,
                                                const int* __restrict__ firstp,
                                                const int* __restrict__ lastp,
                                                const float* __restrict__ ws,
                                                const float* __restrict__ amask,
                                                float* __restrict__ dout) {
    if (blockIdx.x < BG * 16 * 8) {
        if (part == nullptr) return;
        const int b   = blockIdx.x >> 7;
        const int elc = (blockIdx.x >> 3) & 15;
        const int sp  = blockIdx.x & 7;
        const int el  = elc * 256 + threadIdx.x;   // k*128+c
        const int lo = firstp[b], hi = lastp[b];
        if (lo > hi) return;
        const int count = hi - lo + 1;
        const int per = (count + 7) >> 3;
        const int t0 = lo + sp * per;
        if (t0 > hi) return;
        int t1 = t0 + per - 1; if (t1 > hi) t1 = hi;
        float s0 = 0.f, s1 = 0.f;
        int tt = t0;
        for (; tt + 1 <= t1; tt += 2) {
            s0 += (float)part[(size_t)tt * 4096 + el];
            s1 += (float)part[(size_t)(tt + 1) * 4096 + el];
        }
        if (tt <= t1) s0 += (float)part[(size_t)tt * 4096 + el];
        atomicAdd(dout + (size_t)b * 4096 + el, s0 + s1);
        return;
    }

    // ---- finalize losses + centroids (single block) ----
    __shared__ float avg[32], csum[32], cpx[32], cpy[32], csq[32];
    __shared__ float lmu[16][32][2];
    __shared__ float red[4], ered[4];
    const int t = threadIdx.x;

    float esum = 0.f;
    for (int i = t; i < NTILES; i += 256) esum += ws[WS_ENTARR + i];
    esum += __shfl_xor(esum, 1);
    esum += __shfl_xor(esum, 2);
    esum += __shfl_xor(esum, 4);
    esum += __shfl_xor(esum, 8);
    esum += __shfl_xor(esum, 16);
    esum += __shfl_xor(esum, 32);
    if ((t & 63) == 0) ered[t >> 6] = esum;

    if (t < 32) {
        float a = 0.f, px = 0.f, py = 0.f, sq = 0.f;
        for (int b = 0; b < BG; ++b) {
            a  += ws[WS_STAT + 0 * 512 + b * KK + t];
            px += ws[WS_STAT + 1 * 512 + b * KK + t];
            py += ws[WS_STAT + 2 * 512 + b * KK + t];
            sq += ws[WS_STAT + 3 * 512 + b * KK + t];
        }
        csum[t] = a; cpx[t] = px; cpy[t] = py; csq[t] = sq;
        avg[t] = a / (float)NN;
    }
    for (int idx = t; idx < BG * KK; idx += 256) {
        float den = ws[WS_STAT + idx] + EPSF;
        float mx = ws[WS_STAT + 512 + idx] / den;
        float my = ws[WS_STAT + 1024 + idx] / den;
        int b = idx >> 5, k = idx & 31;
        lmu[b][k][0] = mx; lmu[b][k][1] = my;
        dout[MU_OFF + idx * 2] = mx;
        dout[MU_OFF + idx * 2 + 1] = my;
    }
    __syncthreads();
    float sep = 0.f;
    for (int idx = t; idx < BG * KK * KK; idx += 256) {
        int b = idx >> 10, k1 = (idx >> 5) & 31, k2 = idx & 31;
        if (k1 != k2) {
            float dx = lmu[b][k1][0] - lmu[b][k2][0];
            float dy = lmu[b][k1][1] - lmu[b][k2][1];
            sep += 1.f / (dx * dx + dy * dy + 1.f);
        }
    }
    for (int off = 32; off; off >>= 1) sep += __shfl_down(sep, off);
    if ((t & 63) == 0) red[t >> 6] = sep;
    __syncthreads();
    if (t == 0) {
        float sept = red[0] + red[1] + red[2] + red[3];
        float separation = sept / ((float)(KK * (KK - 1)) + EPSF);
        float entropy = -(ered[0] + ered[1] + ered[2] + ered[3]) / (float)NN;
        float diversity = 0.f, pruning = 0.f, msum = 0.f, entavg = 0.f, bal = 0.f, mxa = 0.f, spatial = 0.f;
        const float up = 1.f / (float)KK;
        for (int k = 0; k < KK; ++k) {
            float a = avg[k];
            diversity += up * logf(up / (a + EPSF));
            float mk = amask[k];
            pruning += fabsf(a * (1.f - mk));
            msum += mk;
            entavg -= a * logf(a + EPSF);
            bal += a * logf(a * (float)KK + EPSF);
            mxa = fmaxf(mxa, a);
            float den = csum[k] + EPSF;
            float mux = cpx[k] / den, muy = cpy[k] / den;
            spatial += csq[k] / den - (mux * mux + muy * muy);
        }
        pruning *= up;
        spatial *= up;
        const float lk = logf((float)KK);
        float collapse = ((lk - entavg) / lk + fmaxf(mxa - 2.f / (float)KK, 0.f)) * 2.0f;
        float sparsity = (msum / (float)KK) * 0.01f;
        dout[LOSS_OFF + 0] = entropy;
        dout[LOSS_OFF + 1] = diversity;
        dout[LOSS_OFF + 2] = spatial;
        dout[LOSS_OFF + 3] = pruning;
        dout[LOSS_OFF + 4] = sparsity;
        dout[LOSS_OFF + 5] = 0.f;
        dout[LOSS_OFF + 6] = collapse;
        dout[LOSS_OFF + 7] = bal;
        dout[LOSS_OFF + 8] = separation;
    }
}

extern "C" void kernel_launch(void* const* d_in, const int* in_sizes, int n_in,
                              void* d_out, int out_size, void* d_ws, size_t ws_size,
                              hipStream_t stream) {
    const float* x     = (const float*)d_in[0];
    const int*   batch = (const int*)d_in[1];
    const float* pos   = (const float*)d_in[2];
    const float* gum   = (const float*)d_in[3];
    const float* W1    = (const float*)d_in[4];
    const float* b1    = (const float*)d_in[5];
    const float* W2    = (const float*)d_in[6];
    const float* b2    = (const float*)d_in[7];
    const float* scal  = (const float*)d_in[8];
    const float* amask = (const float*)d_in[9];
    float* dout = (float*)d_out;
    float* ws   = (float*)d_ws;
    _Float16* wW1 = (_Float16*)((char*)d_ws + W1B_OFF_BYTES);
    _Float16* wW2 = (_Float16*)((char*)d_ws + W2B_OFF_BYTES);
    int* firstp = (int*)(ws + WS_FIRST);
    int* lastp  = (int*)(ws + WS_LAST);
    const bool usep = (ws_size >= (size_t)WS_NEEDED_BYTES);
    _Float16* partp = usep ? (_Float16*)((char*)d_ws + WS_PART_BYTE) : nullptr;

    k_prep<<<16, 256, 0, stream>>>(W1, W2, batch, wW1, wW2, firstp, lastp, dout, ws);
    k_assign<<<NTILES, 256, 0, stream>>>(x, batch, pos, gum, b1, b2,
                                         scal, amask, wW1, wW2, dout, ws, partp);
    k_reduce<<<BG * 16 * 8 + 1, 256, 0, stream>>>(partp, firstp, lastp, ws, amask, dout);
}